// Round 10
// baseline (59.763 us; speedup 1.0000x reference)
//
#include <hip/hip_runtime.h>

#define NB 4
#define CB 8
#define DB 196
#define MBd 128
#define KBc 64
#define ROWS (NB*CB*DB)        // 6272
#define RPB2 8                 // rows per k_stats block (2 per wave)
#define GRID2 (ROWS/RPB2)      // 784
#define RPB 7                  // fallback path
#define GRID (ROWS/RPB)        // 896
#define CNTF 6422528.0f        // elements per channel

typedef float floatx4 __attribute__((ext_vector_type(4)));

__device__ __forceinline__ float dot4(floatx4 a, floatx4 b){
    return fmaf(a.x,b.x, fmaf(a.y,b.y, fmaf(a.z,b.z, a.w*b.w)));
}

// ================= FAST PATH (~1.66 MB ws) =================
// K1 v2: ZERO cross-lane ops. Transposed centroids in LDS; lane k owns cluster k.
// Outputs: rn_ws (k-ordered, coalesced), xrn_ws, sv_ws (per-row sum of v).
__global__ __launch_bounds__(256) void k_stats(const float* __restrict__ x,
                                               const float* __restrict__ cent,
                                               float* __restrict__ rn_ws,
                                               float* __restrict__ xrn_ws,
                                               float* __restrict__ sv_ws)
{
    __shared__ floatx4 ct4[32*65];      // transposed centroids [m4][k], stride 65 (33.3 KB)
    __shared__ floatx4 xs4[RPB2*32];    // 8 rows of x (4 KB)
    __shared__ float   svbuf[RPB2*65];  // per-(row,k) sv contributions (2 KB)

    const int t  = threadIdx.x;
    const int rb = blockIdx.x * RPB2;
    const floatx4* c4 = (const floatx4*)cent;
    const floatx4* xg = (const floatx4*)x;

    // stage centroids transposed: linear idx = k*32+m4 -> ct4[m4*65+k]
#pragma unroll
    for (int i = 0; i < 8; ++i) {
        const int idx = i*256 + t;
        const int k = idx >> 5, m4 = idx & 31;
        ct4[m4*65 + k] = c4[idx];
    }
    xs4[t] = xg[rb*32 + t];             // 8 rows x 32 float4, coalesced
    __syncthreads();

    const int lane = t & 63, w = t >> 6;

    // per-lane centroid stats (redundant per wave; one-time)
    float ssck = 0.f, opck = 1.f;
#pragma unroll
    for (int m4 = 0; m4 < 32; ++m4) {
        const floatx4 cv = ct4[m4*65 + lane];   // contiguous across lanes -> conflict-free
        ssck += (cv.x+cv.y)+(cv.z+cv.w);
        opck  = fmaf(cv.x,cv.x, fmaf(cv.y,cv.y, fmaf(cv.z,cv.z, fmaf(cv.w,cv.w, opck))));
    }

#pragma unroll
    for (int rr = 0; rr < 2; ++rr) {
        const int r   = w*2 + rr;               // 0..7
        const int row = rb + r;
        float d = 0.f, s2 = 0.f, sx = 0.f;
#pragma unroll
        for (int m4 = 0; m4 < 32; ++m4) {
            const floatx4 xv = xs4[r*32 + m4];  // same-address broadcast (free)
            const floatx4 cv = ct4[m4*65 + lane];
            d  = fmaf(xv.x,cv.x, fmaf(xv.y,cv.y, fmaf(xv.z,cv.z, fmaf(xv.w,cv.w, d))));
            s2 = fmaf(xv.x,xv.x, fmaf(xv.y,xv.y, fmaf(xv.z,xv.z, fmaf(xv.w,xv.w, s2))));
            sx += (xv.x+xv.y)+(xv.z+xv.w);
        }
        const float xrn = __builtin_amdgcn_rsqf(s2);              // |x|^2 >= ~70
        const float rn  = __builtin_amdgcn_rsqf(fmaf(-2.f*xrn, d, opck)); // dist^2 >= ~20
        rn_ws[(size_t)row*KBc + lane] = rn;                       // k-ordered, coalesced
        if (lane == 0) xrn_ws[row] = xrn;
        svbuf[r*65 + lane] = (sx*xrn - ssck) * rn;
    }
    __syncthreads();
    if (t < RPB2) {                 // fixed-order 64-sum per row (padded stride: no conflicts)
        float s = 0.f;
#pragma unroll
        for (int j = 0; j < KBc; ++j) s += svbuf[t*65 + j];
        sv_ws[rb + t] = s;
    }
}

// K_AB: per-channel mean -> aa/bb (8 blocks). Kills k_out's per-block stats reduce.
__global__ __launch_bounds__(256) void k_ab(const float* __restrict__ sv_ws,
                                            const float* __restrict__ gamma,
                                            const float* __restrict__ beta,
                                            float* __restrict__ ab_ws)
{
    __shared__ float red[256];
    const int c = blockIdx.x, t = threadIdx.x;
    float s = 0.f;
    for (int i = t; i < NB*DB; i += 256) {          // 784 rows of this channel
        const int n = i / DB, d = i % DB;
        s += sv_ws[n*(CB*DB) + c*DB + d];
    }
    red[t] = s; __syncthreads();
#pragma unroll
    for (int sd = 128; sd >= 1; sd >>= 1) {
        if (t < sd) red[t] += red[t+sd];
        __syncthreads();
    }
    if (t == 0) {
        const float mean = red[0] / CNTF;
        const float var  = 0.0078125f - mean*mean;   // E[v^2] exact
        const float istd = __builtin_amdgcn_rsqf(var + 1e-5f);
        const float aa = istd * gamma[c];
        ab_ws[2*c]   = aa;
        ab_ws[2*c+1] = beta[c] - mean * aa;
    }
}

// K2 v5: barrier-free pure stream. 1KB contiguous wave-stores.
__global__ __launch_bounds__(256) void k_out(const float* __restrict__ x,
                                             const float* __restrict__ cent,
                                             const float* __restrict__ rn_ws,
                                             const float* __restrict__ xrn_ws,
                                             const float* __restrict__ sv_ws,
                                             const float* __restrict__ ab_ws,
                                             float* __restrict__ out)
{
    const int t   = threadIdx.x;
    const int row = blockIdx.x;
    const int c   = (row / DB) % CB;
    const int l = t & 63, w = t >> 6, li2 = l & 31, hi = l >> 5;
    const floatx4* c4 = (const floatx4*)cent;
    const floatx4* xg = (const floatx4*)x;

    const floatx4 xa  = xg[row*32 + li2];
    const float   xrn = xrn_ws[row];
    const float   SVr = sv_ws[row];
    const float   aa  = ab_ws[2*c];
    const float   bb  = ab_ws[2*c+1];
    floatx4 cv[8];
    float   rnv[8];
#pragma unroll
    for (int it = 0; it < 8; ++it) {
        const int k = it*8 + w*2 + hi;
        cv[it]  = c4[k*32 + li2];
        rnv[it] = rn_ws[(size_t)row*KBc + k];    // k-ordered: 2 distinct addrs per wave
    }

    const float rni = __builtin_amdgcn_rsqf(
        fmaf(2.f*aa*bb, SVr, fmaf(64.f*aa, aa, 8192.f*bb*bb)));
    const float f1  = aa * rni;
    const float c2v = bb * rni;
    const floatx4 va = xa * xrn;

    floatx4* outr = (floatx4*)out + (size_t)row*2048;
#pragma unroll
    for (int it = 0; it < 8; ++it) {
        const int k = it*8 + w*2 + hi;
        const float cc = f1 * rnv[it];
        floatx4 o1;
        o1.x = fmaf(va.x - cv[it].x, cc, c2v);
        o1.y = fmaf(va.y - cv[it].y, cc, c2v);
        o1.z = fmaf(va.z - cv[it].z, cc, c2v);
        o1.w = fmaf(va.w - cv[it].w, cc, c2v);
        outr[k*32 + li2] = o1;                   // 1KB contiguous per wave-instruction
    }
}

// ================= FALLBACK PATH (round-5 proven, ~29 KB ws) =================
__global__ __launch_bounds__(256) void k_stats_f(const float* __restrict__ x,
                                                 const float* __restrict__ cent,
                                                 float* __restrict__ sv_ws,
                                                 float* __restrict__ partial,
                                                 float* __restrict__ opc_ws)
{
    __shared__ float cs[KBc*MBd];
    __shared__ float sopc[KBc];
    __shared__ float ssc[KBc];
    __shared__ float sp1[256], sp2[256];
    __shared__ float svp[RPB*4];
    __shared__ float sv7[RPB];

    const int t  = threadIdx.x;
    const int rb = blockIdx.x * RPB;
    const floatx4* c4 = (const floatx4*)cent;
    floatx4* cs4 = (floatx4*)cs;
#pragma unroll
    for (int i = 0; i < 8; ++i) cs4[i*256 + t] = c4[i*256 + t];
    __syncthreads();
    {
        const int kk = t >> 2, q = t & 3;
        const floatx4* crow = &cs4[kk*32 + q*8];
        float ps = 0.f, pc = 0.f;
#pragma unroll
        for (int f = 0; f < 8; ++f) { floatx4 v = crow[f]; ps += (v.x+v.y)+(v.z+v.w); pc += dot4(v,v); }
        sp1[t] = ps; sp2[t] = pc;
    }
    __syncthreads();
    if (t < KBc) {
        ssc[t]  = (sp1[4*t]+sp1[4*t+1])+(sp1[4*t+2]+sp1[4*t+3]);
        sopc[t] = 1.0f + ((sp2[4*t]+sp2[4*t+1])+(sp2[4*t+2]+sp2[4*t+3]));
    }
    __syncthreads();
    if (blockIdx.x == 0 && t < KBc) opc_ws[t] = sopc[t];

    const int l = t & 63, w = t >> 6, g = (l >> 4), li = l & 15;
    const floatx4* xg = (const floatx4*)x;
    for (int ri = 0; ri < RPB; ++ri) {
        const int row = rb + ri;
        floatx4 xa = xg[row*32 + li];
        floatx4 xb = xg[row*32 + 16 + li];
        float s2 = dot4(xa,xa) + dot4(xb,xb);
        float sx = ((xa.x+xa.y)+(xa.z+xa.w)) + ((xb.x+xb.y)+(xb.z+xb.w));
#pragma unroll
        for (int o = 8; o >= 1; o >>= 1) { s2 += __shfl_xor(s2,o,64); sx += __shfl_xor(sx,o,64); }
        const float xrn = __builtin_amdgcn_rsqf(s2);
        const float Sx  = sx * xrn;
        float sva = 0.f;
#pragma unroll
        for (int it = 0; it < 4; ++it) {
            const int k = it*16 + w*4 + g;
            float d = dot4(xa, cs4[k*32+li]) + dot4(xb, cs4[k*32+16+li]);
#pragma unroll
            for (int o = 8; o >= 1; o >>= 1) d += __shfl_xor(d,o,64);
            const float dn = xrn * d;
            const float rn = __builtin_amdgcn_rsqf(fmaf(-2.f, dn, sopc[k]));
            sva = fmaf(Sx - ssc[k], rn, sva);
        }
#pragma unroll
        for (int o = 32; o >= 1; o >>= 1) sva += __shfl_xor(sva,o,64);
        if (l == 0) svp[ri*4 + w] = sva * 0.0625f;
    }
    __syncthreads();
    if (t < RPB) {
        float s = (svp[4*t]+svp[4*t+1])+(svp[4*t+2]+svp[4*t+3]);
        sv_ws[rb + t] = s;
        sv7[t] = s;
    }
    __syncthreads();
    if (t == 0) {
        float s = 0.f;
#pragma unroll
        for (int i = 0; i < RPB; ++i) s += sv7[i];
        partial[blockIdx.x] = s;
    }
}

__global__ __launch_bounds__(256) void k_out_f(const float* __restrict__ x,
                                               const float* __restrict__ cent,
                                               const float* __restrict__ sv_ws,
                                               const float* __restrict__ partial,
                                               const float* __restrict__ opc_ws,
                                               const float* __restrict__ gamma,
                                               const float* __restrict__ beta,
                                               float* __restrict__ out)
{
    __shared__ float cs[KBc*MBd];
    __shared__ float sopc[KBc];
    __shared__ float sab[2];
    const int t  = threadIdx.x;
    const int rb = blockIdx.x * RPB;
    const int c  = (blockIdx.x / 28) % CB;
    const floatx4* c4 = (const floatx4*)cent;
    floatx4* cs4 = (floatx4*)cs;
#pragma unroll
    for (int i = 0; i < 8; ++i) cs4[i*256 + t] = c4[i*256 + t];
    if (t >= 64 && t < 128) sopc[t-64] = opc_ws[t-64];
    if (t < 64) {
        float s1 = 0.f;
        if (t < 56) {
            const int j0 = t, j1 = t + 56;
            const int b0 = (j0/28)*224 + c*28 + (j0%28);
            const int b1 = (j1/28)*224 + c*28 + (j1%28);
            s1 = partial[b0] + partial[b1];
        }
#pragma unroll
        for (int o = 32; o >= 1; o >>= 1) s1 += __shfl_xor(s1,o,64);
        if (t == 0) {
            const float mean = s1 / CNTF;
            const float var  = 0.0078125f - mean*mean;
            const float istd = __builtin_amdgcn_rsqf(var + 1e-5f);
            const float aa = istd * gamma[c];
            const float bb = beta[c] - mean * aa;
            sab[0] = aa; sab[1] = bb;
        }
    }
    __syncthreads();
    const float aa = sab[0], bb = sab[1];

    const int l = t & 63, w = t >> 6, g = (l >> 4), li = l & 15;
    const floatx4* xg = (const floatx4*)x;
    for (int ri = 0; ri < RPB; ++ri) {
        const int row = rb + ri;
        floatx4 xa = xg[row*32 + li];
        floatx4 xb = xg[row*32 + 16 + li];
        float s2 = dot4(xa,xa) + dot4(xb,xb);
#pragma unroll
        for (int o = 8; o >= 1; o >>= 1) s2 += __shfl_xor(s2,o,64);
        const float xrn = __builtin_amdgcn_rsqf(s2);
        const floatx4 va = xa * xrn, vb = xb * xrn;
        const float SVr = sv_ws[row];
        const float q   = fmaf(64.f*aa, aa, fmaf(2.f*aa*bb, SVr, 8192.f*bb*bb));
        const float rni = __builtin_amdgcn_rsqf(q);
        const float f1  = aa * rni;
        const float c2  = bb * rni;
        floatx4* outr = (floatx4*)out + (size_t)row*2048;
#pragma unroll
        for (int it = 0; it < 4; ++it) {
            const int k = it*16 + w*4 + g;
            const floatx4 cca = cs4[k*32+li];
            const floatx4 ccb = cs4[k*32+16+li];
            float d = dot4(va,cca) + dot4(vb,ccb);
#pragma unroll
            for (int o = 8; o >= 1; o >>= 1) d += __shfl_xor(d,o,64);
            const float rn = __builtin_amdgcn_rsqf(fmaf(-2.f, d, sopc[k]));
            const float cc = f1 * rn;
            floatx4 o1, o2;
            o1.x = fmaf(va.x - cca.x, cc, c2); o1.y = fmaf(va.y - cca.y, cc, c2);
            o1.z = fmaf(va.z - cca.z, cc, c2); o1.w = fmaf(va.w - cca.w, cc, c2);
            o2.x = fmaf(vb.x - ccb.x, cc, c2); o2.y = fmaf(vb.y - ccb.y, cc, c2);
            o2.z = fmaf(vb.z - ccb.z, cc, c2); o2.w = fmaf(vb.w - ccb.w, cc, c2);
            outr[k*32 + li]      = o1;
            outr[k*32 + 16 + li] = o2;
        }
    }
}

extern "C" void kernel_launch(void* const* d_in, const int* in_sizes, int n_in,
                              void* d_out, int out_size, void* d_ws, size_t ws_size,
                              hipStream_t stream)
{
    const float* x     = (const float*)d_in[0];
    // d_in[1]=conv_w, d_in[2]=conv_b : provably unused (softmax cancels in intra-norm)
    const float* cent  = (const float*)d_in[3];
    const float* gamma = (const float*)d_in[4];
    const float* beta  = (const float*)d_in[5];
    float* out = (float*)d_out;

    const size_t need = (size_t)(ROWS*KBc + 2*ROWS + 16) * sizeof(float);
    if (ws_size >= need) {
        float* rn_ws   = (float*)d_ws;                 // 6272*64 (k-ordered)
        float* xrn_ws  = rn_ws + (size_t)ROWS*KBc;     // 6272
        float* sv_ws   = xrn_ws + ROWS;                // 6272
        float* ab_ws   = sv_ws + ROWS;                 // 16
        hipLaunchKernelGGL(k_stats, dim3(GRID2), dim3(256), 0, stream,
                           x, cent, rn_ws, xrn_ws, sv_ws);
        hipLaunchKernelGGL(k_ab,    dim3(CB),    dim3(256), 0, stream,
                           sv_ws, gamma, beta, ab_ws);
        hipLaunchKernelGGL(k_out,   dim3(ROWS),  dim3(256), 0, stream,
                           x, cent, rn_ws, xrn_ws, sv_ws, ab_ws, out);
    } else {
        float* sv_ws   = (float*)d_ws;
        float* partial = sv_ws + ROWS;
        float* opc_ws  = partial + GRID;
        hipLaunchKernelGGL(k_stats_f, dim3(GRID), dim3(256), 0, stream,
                           x, cent, sv_ws, partial, opc_ws);
        hipLaunchKernelGGL(k_out_f,   dim3(GRID), dim3(256), 0, stream,
                           x, cent, sv_ws, partial, opc_ws, gamma, beta, out);
    }
}

// Round 11
// 51.875 us; speedup vs baseline: 1.1520x; 1.1520x over previous
//
#include <hip/hip_runtime.h>

#define NB 4
#define CB 8
#define DB 196
#define MBd 128
#define KBc 64
#define ROWS (NB*CB*DB)        // 6272
#define RROWS 16               // rows per k_stats block
#define GRID3 (ROWS/RROWS)     // 392
#define RPB 7                  // fallback path
#define GRID (ROWS/RPB)        // 896
#define CNTF 6422528.0f        // elements per channel

typedef float floatx4 __attribute__((ext_vector_type(4)));

__device__ __forceinline__ float dot4(floatx4 a, floatx4 b){
    return fmaf(a.x,b.x, fmaf(a.y,b.y, fmaf(a.z,b.z, a.w*b.w)));
}

// ================= FAST PATH (~1.66 MB ws) =================
// K1 v3: lane k holds centroid k in REGISTERS; x rows broadcast from LDS;
// row stats (s2,sx) computed once cooperatively. No shuffles, minimal LDS traffic.
__global__ __launch_bounds__(256) void k_stats(const float* __restrict__ x,
                                               const float* __restrict__ cent,
                                               float* __restrict__ rn_ws,
                                               float* __restrict__ xrn_ws,
                                               float* __restrict__ sv_ws)
{
    __shared__ floatx4 xs4[RROWS*32];      // 8 KB: 16 rows of x
    __shared__ float p2[256], px[256];
    __shared__ float rxrn[RROWS], rsxn[RROWS];
    __shared__ float svbuf[RROWS*68];      // padded stride 68

    const int t    = threadIdx.x;
    const int rb   = blockIdx.x * RROWS;
    const int lane = t & 63;               // k
    const int rs   = t >> 6;               // row slot 0..3
    const floatx4* c4 = (const floatx4*)cent;
    const floatx4* xg = (const floatx4*)x;

    // centroid row k -> registers (once per block; 32KB/wave total, L1/L2-resident)
    floatx4 creg[32];
#pragma unroll
    for (int m4 = 0; m4 < 32; ++m4) creg[m4] = c4[lane*32 + m4];

    // stage 16 rows of x (512 float4, coalesced)
    xs4[t]       = xg[rb*32 + t];
    xs4[256 + t] = xg[rb*32 + 256 + t];
    __syncthreads();

    // per-row s2/sx: thread t -> row t/16, segment t%16 (8 floats)
    {
        const int r = t >> 4, seg = t & 15;
        const floatx4 a = xs4[r*32 + seg*2];
        const floatx4 b = xs4[r*32 + seg*2 + 1];
        p2[t] = dot4(a,a) + dot4(b,b);
        px[t] = ((a.x+a.y)+(a.z+a.w)) + ((b.x+b.y)+(b.z+b.w));
    }
    __syncthreads();
    if (t < RROWS) {
        float s2 = 0.f, sx = 0.f;
#pragma unroll
        for (int j = 0; j < 16; ++j) { s2 += p2[t*16+j]; sx += px[t*16+j]; }
        const float xrn = __builtin_amdgcn_rsqf(s2);   // |x|^2 >= ~70, clamp inert
        rxrn[t] = xrn;
        rsxn[t] = sx * xrn;
        xrn_ws[rb + t] = xrn;
    }

    // per-k centroid stats from registers (once per block)
    float ssck = 0.f, opck = 1.f;
#pragma unroll
    for (int m4 = 0; m4 < 32; ++m4) {
        const floatx4 cv = creg[m4];
        ssck += (cv.x+cv.y)+(cv.z+cv.w);
        opck  = fmaf(cv.x,cv.x, fmaf(cv.y,cv.y, fmaf(cv.z,cv.z, fmaf(cv.w,cv.w, opck))));
    }
    __syncthreads();

    // 4 rows per thread (rows rs, rs+4, rs+8, rs+12): d = xn . c_k via broadcasts
#pragma unroll
    for (int rr = 0; rr < 4; ++rr) {
        const int r = rs + rr*4;
        float d = 0.f;
#pragma unroll
        for (int m4 = 0; m4 < 32; ++m4) {
            const floatx4 xv = xs4[r*32 + m4];   // same-address broadcast across wave
            d = fmaf(xv.x,creg[m4].x, fmaf(xv.y,creg[m4].y,
                 fmaf(xv.z,creg[m4].z, fmaf(xv.w,creg[m4].w, d))));
        }
        const float xrn = rxrn[r];
        const float rn  = __builtin_amdgcn_rsqf(fmaf(-2.f*xrn, d, opck)); // dist^2 >= ~20
        rn_ws[(size_t)(rb + r)*KBc + lane] = rn;       // k-ordered, coalesced
        svbuf[r*68 + lane] = (rsxn[r] - ssck) * rn;
    }
    __syncthreads();
    if (t < RROWS) {           // fixed-order 64-sum per row
        float s = 0.f;
#pragma unroll
        for (int j = 0; j < KBc; ++j) s += svbuf[t*68 + j];
        sv_ws[rb + t] = s;
    }
}

// K_AB: per-channel mean -> aa/bb (8 blocks).
__global__ __launch_bounds__(256) void k_ab(const float* __restrict__ sv_ws,
                                            const float* __restrict__ gamma,
                                            const float* __restrict__ beta,
                                            float* __restrict__ ab_ws)
{
    __shared__ float red[256];
    const int c = blockIdx.x, t = threadIdx.x;
    float s = 0.f;
    for (int i = t; i < NB*DB; i += 256) {
        const int n = i / DB, d = i % DB;
        s += sv_ws[n*(CB*DB) + c*DB + d];
    }
    red[t] = s; __syncthreads();
#pragma unroll
    for (int sd = 128; sd >= 1; sd >>= 1) {
        if (t < sd) red[t] += red[t+sd];
        __syncthreads();
    }
    if (t == 0) {
        const float mean = red[0] / CNTF;
        const float var  = 0.0078125f - mean*mean;   // E[v^2] exact
        const float istd = __builtin_amdgcn_rsqf(var + 1e-5f);
        const float aa = istd * gamma[c];
        ab_ws[2*c]   = aa;
        ab_ws[2*c+1] = beta[c] - mean * aa;
    }
}

// K2 v5 (unchanged): barrier-free pure stream, 1KB contiguous wave-stores.
__global__ __launch_bounds__(256) void k_out(const float* __restrict__ x,
                                             const float* __restrict__ cent,
                                             const float* __restrict__ rn_ws,
                                             const float* __restrict__ xrn_ws,
                                             const float* __restrict__ sv_ws,
                                             const float* __restrict__ ab_ws,
                                             float* __restrict__ out)
{
    const int t   = threadIdx.x;
    const int row = blockIdx.x;
    const int c   = (row / DB) % CB;
    const int l = t & 63, w = t >> 6, li2 = l & 31, hi = l >> 5;
    const floatx4* c4 = (const floatx4*)cent;
    const floatx4* xg = (const floatx4*)x;

    const floatx4 xa  = xg[row*32 + li2];
    const float   xrn = xrn_ws[row];
    const float   SVr = sv_ws[row];
    const float   aa  = ab_ws[2*c];
    const float   bb  = ab_ws[2*c+1];
    floatx4 cv[8];
    float   rnv[8];
#pragma unroll
    for (int it = 0; it < 8; ++it) {
        const int k = it*8 + w*2 + hi;
        cv[it]  = c4[k*32 + li2];
        rnv[it] = rn_ws[(size_t)row*KBc + k];
    }

    const float rni = __builtin_amdgcn_rsqf(
        fmaf(2.f*aa*bb, SVr, fmaf(64.f*aa, aa, 8192.f*bb*bb)));
    const float f1  = aa * rni;
    const float c2v = bb * rni;
    const floatx4 va = xa * xrn;

    floatx4* outr = (floatx4*)out + (size_t)row*2048;
#pragma unroll
    for (int it = 0; it < 8; ++it) {
        const int k = it*8 + w*2 + hi;
        const float cc = f1 * rnv[it];
        floatx4 o1;
        o1.x = fmaf(va.x - cv[it].x, cc, c2v);
        o1.y = fmaf(va.y - cv[it].y, cc, c2v);
        o1.z = fmaf(va.z - cv[it].z, cc, c2v);
        o1.w = fmaf(va.w - cv[it].w, cc, c2v);
        outr[k*32 + li2] = o1;
    }
}

// ================= FALLBACK PATH (round-5 proven, ~29 KB ws) =================
__global__ __launch_bounds__(256) void k_stats_f(const float* __restrict__ x,
                                                 const float* __restrict__ cent,
                                                 float* __restrict__ sv_ws,
                                                 float* __restrict__ partial,
                                                 float* __restrict__ opc_ws)
{
    __shared__ float cs[KBc*MBd];
    __shared__ float sopc[KBc];
    __shared__ float ssc[KBc];
    __shared__ float sp1[256], sp2[256];
    __shared__ float svp[RPB*4];
    __shared__ float sv7[RPB];

    const int t  = threadIdx.x;
    const int rb = blockIdx.x * RPB;
    const floatx4* c4 = (const floatx4*)cent;
    floatx4* cs4 = (floatx4*)cs;
#pragma unroll
    for (int i = 0; i < 8; ++i) cs4[i*256 + t] = c4[i*256 + t];
    __syncthreads();
    {
        const int kk = t >> 2, q = t & 3;
        const floatx4* crow = &cs4[kk*32 + q*8];
        float ps = 0.f, pc = 0.f;
#pragma unroll
        for (int f = 0; f < 8; ++f) { floatx4 v = crow[f]; ps += (v.x+v.y)+(v.z+v.w); pc += dot4(v,v); }
        sp1[t] = ps; sp2[t] = pc;
    }
    __syncthreads();
    if (t < KBc) {
        ssc[t]  = (sp1[4*t]+sp1[4*t+1])+(sp1[4*t+2]+sp1[4*t+3]);
        sopc[t] = 1.0f + ((sp2[4*t]+sp2[4*t+1])+(sp2[4*t+2]+sp2[4*t+3]));
    }
    __syncthreads();
    if (blockIdx.x == 0 && t < KBc) opc_ws[t] = sopc[t];

    const int l = t & 63, w = t >> 6, g = (l >> 4), li = l & 15;
    const floatx4* xg = (const floatx4*)x;
    for (int ri = 0; ri < RPB; ++ri) {
        const int row = rb + ri;
        floatx4 xa = xg[row*32 + li];
        floatx4 xb = xg[row*32 + 16 + li];
        float s2 = dot4(xa,xa) + dot4(xb,xb);
        float sx = ((xa.x+xa.y)+(xa.z+xa.w)) + ((xb.x+xb.y)+(xb.z+xb.w));
#pragma unroll
        for (int o = 8; o >= 1; o >>= 1) { s2 += __shfl_xor(s2,o,64); sx += __shfl_xor(sx,o,64); }
        const float xrn = __builtin_amdgcn_rsqf(s2);
        const float Sx  = sx * xrn;
        float sva = 0.f;
#pragma unroll
        for (int it = 0; it < 4; ++it) {
            const int k = it*16 + w*4 + g;
            float d = dot4(xa, cs4[k*32+li]) + dot4(xb, cs4[k*32+16+li]);
#pragma unroll
            for (int o = 8; o >= 1; o >>= 1) d += __shfl_xor(d,o,64);
            const float dn = xrn * d;
            const float rn = __builtin_amdgcn_rsqf(fmaf(-2.f, dn, sopc[k]));
            sva = fmaf(Sx - ssc[k], rn, sva);
        }
#pragma unroll
        for (int o = 32; o >= 1; o >>= 1) sva += __shfl_xor(sva,o,64);
        if (l == 0) svp[ri*4 + w] = sva * 0.0625f;
    }
    __syncthreads();
    if (t < RPB) {
        float s = (svp[4*t]+svp[4*t+1])+(svp[4*t+2]+svp[4*t+3]);
        sv_ws[rb + t] = s;
        sv7[t] = s;
    }
    __syncthreads();
    if (t == 0) {
        float s = 0.f;
#pragma unroll
        for (int i = 0; i < RPB; ++i) s += sv7[i];
        partial[blockIdx.x] = s;
    }
}

__global__ __launch_bounds__(256) void k_out_f(const float* __restrict__ x,
                                               const float* __restrict__ cent,
                                               const float* __restrict__ sv_ws,
                                               const float* __restrict__ partial,
                                               const float* __restrict__ opc_ws,
                                               const float* __restrict__ gamma,
                                               const float* __restrict__ beta,
                                               float* __restrict__ out)
{
    __shared__ float cs[KBc*MBd];
    __shared__ float sopc[KBc];
    __shared__ float sab[2];
    const int t  = threadIdx.x;
    const int rb = blockIdx.x * RPB;
    const int c  = (blockIdx.x / 28) % CB;
    const floatx4* c4 = (const floatx4*)cent;
    floatx4* cs4 = (floatx4*)cs;
#pragma unroll
    for (int i = 0; i < 8; ++i) cs4[i*256 + t] = c4[i*256 + t];
    if (t >= 64 && t < 128) sopc[t-64] = opc_ws[t-64];
    if (t < 64) {
        float s1 = 0.f;
        if (t < 56) {
            const int j0 = t, j1 = t + 56;
            const int b0 = (j0/28)*224 + c*28 + (j0%28);
            const int b1 = (j1/28)*224 + c*28 + (j1%28);
            s1 = partial[b0] + partial[b1];
        }
#pragma unroll
        for (int o = 32; o >= 1; o >>= 1) s1 += __shfl_xor(s1,o,64);
        if (t == 0) {
            const float mean = s1 / CNTF;
            const float var  = 0.0078125f - mean*mean;
            const float istd = __builtin_amdgcn_rsqf(var + 1e-5f);
            const float aa = istd * gamma[c];
            const float bb = beta[c] - mean * aa;
            sab[0] = aa; sab[1] = bb;
        }
    }
    __syncthreads();
    const float aa = sab[0], bb = sab[1];

    const int l = t & 63, w = t >> 6, g = (l >> 4), li = l & 15;
    const floatx4* xg = (const floatx4*)x;
    for (int ri = 0; ri < RPB; ++ri) {
        const int row = rb + ri;
        floatx4 xa = xg[row*32 + li];
        floatx4 xb = xg[row*32 + 16 + li];
        float s2 = dot4(xa,xa) + dot4(xb,xb);
#pragma unroll
        for (int o = 8; o >= 1; o >>= 1) s2 += __shfl_xor(s2,o,64);
        const float xrn = __builtin_amdgcn_rsqf(s2);
        const floatx4 va = xa * xrn, vb = xb * xrn;
        const float SVr = sv_ws[row];
        const float q   = fmaf(64.f*aa, aa, fmaf(2.f*aa*bb, SVr, 8192.f*bb*bb));
        const float rni = __builtin_amdgcn_rsqf(q);
        const float f1  = aa * rni;
        const float c2  = bb * rni;
        floatx4* outr = (floatx4*)out + (size_t)row*2048;
#pragma unroll
        for (int it = 0; it < 4; ++it) {
            const int k = it*16 + w*4 + g;
            const floatx4 cca = cs4[k*32+li];
            const floatx4 ccb = cs4[k*32+16+li];
            float d = dot4(va,cca) + dot4(vb,ccb);
#pragma unroll
            for (int o = 8; o >= 1; o >>= 1) d += __shfl_xor(d,o,64);
            const float rn = __builtin_amdgcn_rsqf(fmaf(-2.f, d, sopc[k]));
            const float cc = f1 * rn;
            floatx4 o1, o2;
            o1.x = fmaf(va.x - cca.x, cc, c2); o1.y = fmaf(va.y - cca.y, cc, c2);
            o1.z = fmaf(va.z - cca.z, cc, c2); o1.w = fmaf(va.w - cca.w, cc, c2);
            o2.x = fmaf(vb.x - ccb.x, cc, c2); o2.y = fmaf(vb.y - ccb.y, cc, c2);
            o2.z = fmaf(vb.z - ccb.z, cc, c2); o2.w = fmaf(vb.w - ccb.w, cc, c2);
            outr[k*32 + li]      = o1;
            outr[k*32 + 16 + li] = o2;
        }
    }
}

extern "C" void kernel_launch(void* const* d_in, const int* in_sizes, int n_in,
                              void* d_out, int out_size, void* d_ws, size_t ws_size,
                              hipStream_t stream)
{
    const float* x     = (const float*)d_in[0];
    // d_in[1]=conv_w, d_in[2]=conv_b : provably unused (softmax cancels in intra-norm)
    const float* cent  = (const float*)d_in[3];
    const float* gamma = (const float*)d_in[4];
    const float* beta  = (const float*)d_in[5];
    float* out = (float*)d_out;

    const size_t need = (size_t)(ROWS*KBc + 2*ROWS + 16) * sizeof(float);
    if (ws_size >= need) {
        float* rn_ws   = (float*)d_ws;                 // 6272*64 (k-ordered)
        float* xrn_ws  = rn_ws + (size_t)ROWS*KBc;     // 6272
        float* sv_ws   = xrn_ws + ROWS;                // 6272
        float* ab_ws   = sv_ws + ROWS;                 // 16
        hipLaunchKernelGGL(k_stats, dim3(GRID3), dim3(256), 0, stream,
                           x, cent, rn_ws, xrn_ws, sv_ws);
        hipLaunchKernelGGL(k_ab,    dim3(CB),    dim3(256), 0, stream,
                           sv_ws, gamma, beta, ab_ws);
        hipLaunchKernelGGL(k_out,   dim3(ROWS),  dim3(256), 0, stream,
                           x, cent, rn_ws, xrn_ws, sv_ws, ab_ws, out);
    } else {
        float* sv_ws   = (float*)d_ws;
        float* partial = sv_ws + ROWS;
        float* opc_ws  = partial + GRID;
        hipLaunchKernelGGL(k_stats_f, dim3(GRID), dim3(256), 0, stream,
                           x, cent, sv_ws, partial, opc_ws);
        hipLaunchKernelGGL(k_out_f,   dim3(GRID), dim3(256), 0, stream,
                           x, cent, sv_ws, partial, opc_ws, gamma, beta, out);
    }
}